// Round 7
// baseline (195.798 us; speedup 1.0000x reference)
//
#include <hip/hip_runtime.h>
#include <hip/hip_bf16.h>

#define B_TOT 65536
#define S 9
#define D 20
#define DFF 512
#define EPS 1e-5f

typedef short bf16x8 __attribute__((ext_vector_type(8)));
typedef float f32x4 __attribute__((ext_vector_type(4)));

// ws layout (enumeration units: shorts for frag tables, floats for bias):
//   PQKV  [4ct][64][8] bf16 @ short 0     : A-frags of [Wq|Wk|Wv]^T: row j=ct*16+cl, k=d=8g+jj
//   PWOA  [2ct][64][8] bf16 @ short 2048  : A-frags of Wo^T: row j, k=d
//   BQKV  f32[64]  @ float 1536           : bq|bk|bv concat, pad 0  (byte 6144)
//   BO4   f32[64]  @ float 1600           : bo padded to 64          (byte 6400)
//   PA1   [32frag][64][8] @ short 3328    : W1 A-frags, PERMUTED (round-5 layout, verified)
//   PB2   [32frag][64][8] @ short 19712   : W2 B-frags (round-5 layout, verified)
#define SH_PQKV 0
#define SH_PWOA 2048
#define FL_BQKV 1536
#define FL_BO4 1600
#define SH_PA1 3328
#define SH_PB2 19712
#define PREP_TOTAL (2048 + 1024 + 128 + 16384 + 16384)

__device__ __forceinline__ unsigned short f2bf(float f) {
  union { __hip_bfloat16 h; unsigned short u; } v;
  v.h = __float2bfloat16(f);
  return v.u;
}
__device__ __forceinline__ float bf2f(unsigned short h) {
  union { unsigned u; float f; } v; v.u = ((unsigned)h) << 16; return v.f;
}
__device__ __forceinline__ unsigned cvt2(float a, float b) {
  union { __hip_bfloat162 h; unsigned u; } v;
  v.h = __float22bfloat162_rn(make_float2(a, b));
  return v.u;
}
__device__ __forceinline__ void unpk(unsigned u, float& lo, float& hi) {
  union { unsigned v; float f; } a, b;
  a.v = u << 16; b.v = u & 0xffff0000u;
  lo = a.f; hi = b.f;
}
__device__ __forceinline__ void unpack20(uint4 a, uint4 b, uint2 c, float* o) {
  unpk(a.x, o[0], o[1]); unpk(a.y, o[2], o[3]); unpk(a.z, o[4], o[5]); unpk(a.w, o[6], o[7]);
  unpk(b.x, o[8], o[9]); unpk(b.y, o[10], o[11]); unpk(b.z, o[12], o[13]); unpk(b.w, o[14], o[15]);
  unpk(c.x, o[16], o[17]); unpk(c.y, o[18], o[19]);
}

__global__ void prep_kernel(const float* __restrict__ Wq, const float* __restrict__ Wk,
                            const float* __restrict__ Wv, const float* __restrict__ Wo,
                            const float* __restrict__ W1, const float* __restrict__ W2,
                            const float* __restrict__ bq, const float* __restrict__ bk,
                            const float* __restrict__ bv, const float* __restrict__ bo,
                            float* __restrict__ wsf) {
  int stride = gridDim.x * blockDim.x;
  unsigned short* P = (unsigned short*)wsf;
  for (int i = blockIdx.x * blockDim.x + threadIdx.x; i < PREP_TOTAL; i += stride) {
    if (i < 2048) {
      // PQKV A-frags: row j = ct*16+cl, k = d = 8g+jj; element = Wmat[d][j%20]
      int ct = i >> 9, rem = i & 511, l = rem >> 3, jj = rem & 7;
      int g = l >> 4, cl = l & 15;
      int j = ct * 16 + cl, d = 8 * g + jj;
      unsigned short v = 0;
      if (d < 20 && j < 60) {
        int mat = j / 20, jc = j % 20;
        const float* Wsrc = (mat == 0) ? Wq : (mat == 1) ? Wk : Wv;
        v = f2bf(Wsrc[d * 20 + jc]);
      }
      P[SH_PQKV + i] = v;
    } else if (i < 3072) {
      int p = i - 2048;
      int ct = p >> 9, rem = p & 511, l = rem >> 3, jj = rem & 7;
      int g = l >> 4, cl = l & 15;
      int j = ct * 16 + cl, d = 8 * g + jj;
      P[SH_PWOA + p] = (d < 20 && j < 20) ? f2bf(Wo[d * 20 + j]) : (unsigned short)0;
    } else if (i < 3200) {
      int j = i - 3072;  // 0..127
      float v = 0.f;
      if (j < 20) v = bq[j];
      else if (j < 40) v = bk[j - 20];
      else if (j < 60) v = bv[j - 40];
      else if (j >= 64 && j < 84) v = bo[j - 64];
      wsf[FL_BQKV + j] = v;
    } else if (i < 3200 + 16384) {
      // PA1: permuted W1 A-fragments (unchanged, verified)
      int j = i - 3200;
      int frag = j >> 9, rem = j & 511;
      int l = rem >> 3, jj = rem & 7;
      int p = frag & 1, q2 = (frag >> 1) & 3, ch = frag >> 3;
      int g2 = l >> 4, cl2 = l & 15;
      int k = 8 * g2 + jj;
      int f = ch * 128 + q2 * 32 + 8 * (cl2 >> 2) + 4 * p + (cl2 & 3);
      P[SH_PA1 + j] = (k < 20) ? f2bf(W1[k * DFF + f]) : (unsigned short)0;
    } else {
      // PB2 (unchanged, verified)
      int j = i - (3200 + 16384);
      int pair = j >> 9, rem = j & 511;
      int l = rem >> 3, jj = rem & 7;
      int g = l >> 4, cl = l & 15;
      int kk = pair >> 1, cc = pair & 1;
      int kg = kk * 32 + 8 * g + jj;
      int d = cc * 16 + cl;
      P[SH_PB2 + j] = (d < 20) ? f2bf(W2[kg * 20 + d]) : (unsigned short)0;
    }
  }
}

// Per-wave LDS slab 10240 B, wave-private (NO __syncthreads):
//   RA (4096 B): bf16 [64 rows][32] rows 64B — sequential lifetimes:
//                Xstage -> q(quads 0..4) -> merged -> ao -> Y
//   RB (6144 B): bf16 kv rows 96B: k quads @ +0..39, v quads @ +48..87
// All overlays fenced with asm memory clobbers (full sched boundary).
// All strides linear (round-4 lesson: no unallocated stagger).
#define SLAB_BYTES 10240
#define RA 0
#define RB 4096

#define FENCE() asm volatile("" ::: "memory")

__global__ __launch_bounds__(256, 4) void encoder_kernel(
    const float* __restrict__ X, const float* __restrict__ ws,
    const float* __restrict__ g1, const float* __restrict__ b1,
    const float* __restrict__ g2, const float* __restrict__ b2,
    float* __restrict__ Out) {
  __shared__ __align__(16) char smem[4 * SLAB_BYTES];

  const unsigned short* P16 = (const unsigned short*)ws;
  const unsigned short* PQKV = P16 + SH_PQKV;
  const unsigned short* PWOA = P16 + SH_PWOA;
  const float* BQKV = ws + FL_BQKV;
  const float* BO4 = ws + FL_BO4;
  const unsigned short* PA1 = P16 + SH_PA1;
  const unsigned short* PB2 = P16 + SH_PB2;

  const int tid = threadIdx.x;
  const int wv = tid >> 6;
  const int lane = tid & 63;
  const int bl = lane / 9;     // 0..7 (7 == pad lane 63)
  const int s = lane - bl * 9;
  const long wb = (long)blockIdx.x * 4 + wv;
  const long bb = wb * 7 + bl;
  const bool active = (bl < 7) && (bb < B_TOT);

  char* slab = smem + wv * SLAB_BYTES;
  const int cl = lane & 15;
  const int g = lane >> 4;
  const f32x4 zero4 = {0.f, 0.f, 0.f, 0.f};

  float x[20];

  // ---------------- stage X bf16 rows (zeros for inactive) -------------------
  {
    if (active) {
      const float4* xr = (const float4*)(X + bb * (S * D) + s * D);
#pragma unroll
      for (int i = 0; i < 5; ++i) {
        float4 t = xr[i];
        x[4 * i + 0] = t.x; x[4 * i + 1] = t.y; x[4 * i + 2] = t.z; x[4 * i + 3] = t.w;
      }
    } else {
#pragma unroll
      for (int i = 0; i < 20; ++i) x[i] = 0.f;
    }
    unsigned u[10];
#pragma unroll
    for (int i = 0; i < 10; ++i) u[i] = cvt2(x[2 * i], x[2 * i + 1]);
    uint4* dst = (uint4*)(slab + RA + lane * 64);
    dst[0] = make_uint4(u[0], u[1], u[2], u[3]);
    dst[1] = make_uint4(u[4], u[5], u[6], u[7]);
    dst[2] = make_uint4(u[8], u[9], 0u, 0u);
    dst[3] = make_uint4(0u, 0u, 0u, 0u);
  }
  FENCE();

  // ---------------- X B-frags (lane: col=16rtc+cl row of X, k-slice 8g..) ----
  bf16x8 xfB[4];
#pragma unroll
  for (int rtc = 0; rtc < 4; ++rtc)
    xfB[rtc] = *(const bf16x8*)(slab + RA + (rtc * 16 + cl) * 64 + g * 16);
  FENCE();  // frag reads before q-quad overlay of RA

  // ---------------- QKV MFMA (swapped): D[j][xrow], packed quad scatter ------
#pragma unroll
  for (int ct = 0; ct < 4; ++ct) {
    bf16x8 wf = *(const bf16x8*)(PQKV + (size_t)(ct * 64 + lane) * 8);
    float4 bq4 = *(const float4*)(BQKV + ct * 16 + 4 * g);  // bias for j-quad
    const int qd = ct * 4 + g;                              // j-quad index
    const int mat = (qd >= 10) ? 2 : ((qd >= 5) ? 1 : 0);
    const int jc4 = qd - 5 * mat;
    const bool qv = qd < 15;
#pragma unroll
    for (int rtc = 0; rtc < 4; ++rtc) {
      f32x4 d = __builtin_amdgcn_mfma_f32_16x16x32_bf16(wf, xfB[rtc], zero4, 0, 0, 0);
      if (qv) {
        const int row = rtc * 16 + cl;
        unsigned u0 = cvt2(d[0] + bq4.x, d[1] + bq4.y);
        unsigned u1 = cvt2(d[2] + bq4.z, d[3] + bq4.w);
        char* p = (mat == 0) ? (slab + RA + row * 64 + jc4 * 8)
                             : (slab + RB + row * 96 + ((mat == 2) ? 48 : 0) + jc4 * 8);
        *(uint2*)p = make_uint2(u0, u1);
      }
    }
  }
  FENCE();  // quad scatters before q/k/v reads

  // ---------------- attention (per-lane row) ---------------------------------
  float ctx[20];
  if (active) {
    float q[20];
    {
      const char* qp = slab + RA + lane * 64;
      uint4 a = *(const uint4*)qp;
      uint4 b = *(const uint4*)(qp + 16);
      uint2 c = *(const uint2*)(qp + 32);
      unpack20(a, b, c, q);
    }
    float sc[4][9];
#pragma unroll
    for (int t = 0; t < 9; ++t) {
      const char* kp = slab + RB + (bl * 9 + t) * 96;
      uint4 a = *(const uint4*)kp;
      uint4 b = *(const uint4*)(kp + 16);
      uint2 c = *(const uint2*)(kp + 32);
      float kt[20];
      unpack20(a, b, c, kt);
#pragma unroll
      for (int h = 0; h < 4; ++h) {
        float d0 = q[h * 5 + 0] * kt[h * 5 + 0] + q[h * 5 + 1] * kt[h * 5 + 1];
        float d1 = q[h * 5 + 2] * kt[h * 5 + 2] + q[h * 5 + 3] * kt[h * 5 + 3];
        sc[h][t] = d0 + d1 + q[h * 5 + 4] * kt[h * 5 + 4];
      }
    }
    float inv4[4];
#pragma unroll
    for (int h = 0; h < 4; ++h) {
      float mx = sc[h][0];
#pragma unroll
      for (int t = 1; t < 9; ++t) mx = fmaxf(mx, sc[h][t]);
      float sum = 0.f;
#pragma unroll
      for (int t = 0; t < 9; ++t) {
        sc[h][t] = __expf((sc[h][t] - mx) * (1.0f / 3.0f));
        sum += sc[h][t];
      }
      inv4[h] = 1.0f / sum;
    }
#pragma unroll
    for (int j = 0; j < 20; ++j) ctx[j] = 0.f;
#pragma unroll
    for (int t = 0; t < 9; ++t) {
      const char* vp = slab + RB + (bl * 9 + t) * 96 + 48;
      uint4 a = *(const uint4*)vp;
      uint4 b = *(const uint4*)(vp + 16);
      uint2 c = *(const uint2*)(vp + 32);
      float vt[20];
      unpack20(a, b, c, vt);
#pragma unroll
      for (int h = 0; h < 4; ++h)
#pragma unroll
        for (int dh = 0; dh < 5; ++dh)
          ctx[h * 5 + dh] += sc[h][t] * vt[h * 5 + dh];
    }
#pragma unroll
    for (int h = 0; h < 4; ++h)
#pragma unroll
      for (int dh = 0; dh < 5; ++dh)
        ctx[h * 5 + dh] *= inv4[h];
  }
  FENCE();  // q/kv reads before merged overlay of RA

  // ---------------- merged-ctx scatter (transpose quirk) ---------------------
  if (active) {
    int m = s;  // merged linear index m = 9*w + s, w = 5h+dh
#pragma unroll
    for (int w = 0; w < 20; ++w) {
      int row = (m * 3277) >> 16;  // m/20 (m < 180)
      int col = m - 20 * row;
      *(unsigned short*)(slab + RA + (bl * 9 + row) * 64 + col * 2) = f2bf(ctx[w]);
      m += 9;
    }
  }
  // zero-pad merged cols 20..31 (every lane owns row `lane`)
  *(uint2*)(slab + RA + lane * 64 + 40) = make_uint2(0u, 0u);
  *(uint4*)(slab + RA + lane * 64 + 48) = make_uint4(0u, 0u, 0u, 0u);
  FENCE();  // merged writes before B-frag reads

  // ---------------- Wo MFMA (swapped), packed quad scatter to ao -------------
  bf16x8 mfB[4];
#pragma unroll
  for (int rtc = 0; rtc < 4; ++rtc)
    mfB[rtc] = *(const bf16x8*)(slab + RA + (rtc * 16 + cl) * 64 + g * 16);
  FENCE();  // mf reads before ao overlay
#pragma unroll
  for (int ct = 0; ct < 2; ++ct) {
    bf16x8 wof = *(const bf16x8*)(PWOA + (size_t)(ct * 64 + lane) * 8);
    float4 bo4 = *(const float4*)(BO4 + ct * 16 + 4 * g);  // padded, always in-bounds
    const int qd = ct * 4 + g;
    const bool qv = qd < 5;  // j < 20
#pragma unroll
    for (int rtc = 0; rtc < 4; ++rtc) {
      f32x4 d = __builtin_amdgcn_mfma_f32_16x16x32_bf16(wof, mfB[rtc], zero4, 0, 0, 0);
      if (qv) {
        const int row = rtc * 16 + cl;
        unsigned u0 = cvt2(d[0] + bo4.x, d[1] + bo4.y);
        unsigned u1 = cvt2(d[2] + bo4.z, d[3] + bo4.w);
        *(uint2*)(slab + RA + row * 64 + qd * 8) = make_uint2(u0, u1);
      }
    }
  }
  FENCE();  // ao writes before ao reads

  // ---------------- LN1 (x still in registers) -------------------------------
  float y[20];
  if (active) {
    const char* ap = slab + RA + lane * 64;
    uint4 a = *(const uint4*)ap;
    uint4 b = *(const uint4*)(ap + 16);
    uint2 c = *(const uint2*)(ap + 32);
    float ao[20];
    unpack20(a, b, c, ao);
    float z[20];
#pragma unroll
    for (int d = 0; d < 20; ++d) z[d] = ao[d] + x[d];
    float t0 = 0.f;
#pragma unroll
    for (int d = 0; d < 20; ++d) t0 += z[d];
    float mean = t0 * (1.0f / 20.0f);
    float var = 0.f;
#pragma unroll
    for (int d = 0; d < 20; ++d) { z[d] -= mean; var += z[d] * z[d]; }
    float rs = rsqrtf(var * (1.0f / 20.0f) + EPS);
#pragma unroll
    for (int d = 0; d < 20; ++d) y[d] = z[d] * rs * g1[d] + b1[d];
  } else {
#pragma unroll
    for (int d = 0; d < 20; ++d) y[d] = 0.f;
  }
  FENCE();  // ao reads before Y overlay

  // ---------------- stage Y bf16 rows ----------------------------------------
  {
    unsigned u[10];
#pragma unroll
    for (int i = 0; i < 10; ++i) u[i] = cvt2(y[2 * i], y[2 * i + 1]);
    uint4* dst = (uint4*)(slab + RA + lane * 64);
    dst[0] = make_uint4(u[0], u[1], u[2], u[3]);
    dst[1] = make_uint4(u[4], u[5], u[6], u[7]);
    dst[2] = make_uint4(u[8], u[9], 0u, 0u);
    dst[3] = make_uint4(0u, 0u, 0u, 0u);
  }
  FENCE();  // Y writes before cross-lane frag reads

  // ---------------- FFN via MFMA (register-resident H, verified flow) --------
  bf16x8 ytf[4];
#pragma unroll
  for (int rt = 0; rt < 4; ++rt)
    ytf[rt] = *(const bf16x8*)(slab + RA + (rt * 16 + cl) * 64 + g * 16);

  f32x4 acc[4][2];
#pragma unroll
  for (int rt = 0; rt < 4; ++rt) { acc[rt][0] = zero4; acc[rt][1] = zero4; }

  for (int ch = 0; ch < 4; ++ch) {
#pragma unroll
    for (int q2 = 0; q2 < 4; ++q2) {
      const int fb = ch * 8 + q2 * 2;
      bf16x8 aw0 = *(const bf16x8*)(PA1 + (size_t)(fb * 64 + lane) * 8);
      bf16x8 aw1 = *(const bf16x8*)(PA1 + (size_t)((fb + 1) * 64 + lane) * 8);
      bf16x8 bw0 = *(const bf16x8*)(PB2 + (size_t)(fb * 64 + lane) * 8);
      bf16x8 bw1 = *(const bf16x8*)(PB2 + (size_t)((fb + 1) * 64 + lane) * 8);
#pragma unroll
      for (int rt = 0; rt < 4; ++rt) {
        f32x4 d0 = __builtin_amdgcn_mfma_f32_16x16x32_bf16(aw0, ytf[rt], zero4, 0, 0, 0);
        f32x4 d1 = __builtin_amdgcn_mfma_f32_16x16x32_bf16(aw1, ytf[rt], zero4, 0, 0, 0);
        union { bf16x8 v; unsigned uu[4]; } af;
        af.uu[0] = cvt2(fmaxf(d0[0], 0.f), fmaxf(d0[1], 0.f));
        af.uu[1] = cvt2(fmaxf(d0[2], 0.f), fmaxf(d0[3], 0.f));
        af.uu[2] = cvt2(fmaxf(d1[0], 0.f), fmaxf(d1[1], 0.f));
        af.uu[3] = cvt2(fmaxf(d1[2], 0.f), fmaxf(d1[3], 0.f));
        acc[rt][0] = __builtin_amdgcn_mfma_f32_16x16x32_bf16(af.v, bw0, acc[rt][0], 0, 0, 0);
        acc[rt][1] = __builtin_amdgcn_mfma_f32_16x16x32_bf16(af.v, bw1, acc[rt][1], 0, 0, 0);
      }
    }
  }

  // ---------------- LN2 in fragment space + store ----------------------------
  const float gg0 = g2[cl], bb0 = b2[cl];
  const float gg1 = (cl < 4) ? g2[16 + cl] : 0.f;
  const float bb1 = (cl < 4) ? b2[16 + cl] : 0.f;
  const long wrbase = wb * 63;
  const long total_rows = (long)B_TOT * S;

#pragma unroll
  for (int rt = 0; rt < 4; ++rt) {
#pragma unroll
    for (int r = 0; r < 4; ++r) {
      const int rrow = rt * 16 + 4 * g + r;
      float y0 = bf2f(*(const unsigned short*)(slab + RA + rrow * 64 + cl * 2));
      float y1 = (cl < 4) ? bf2f(*(const unsigned short*)(slab + RA + rrow * 64 + 32 + cl * 2)) : 0.f;
      float z0 = acc[rt][0][r] + y0;
      float z1 = acc[rt][1][r] + y1;
      float t = z0 + ((cl < 4) ? z1 : 0.f);
      t += __shfl_xor(t, 1, 16);
      t += __shfl_xor(t, 2, 16);
      t += __shfl_xor(t, 4, 16);
      t += __shfl_xor(t, 8, 16);
      float mean = t * (1.0f / 20.0f);
      float c0 = z0 - mean, c1 = z1 - mean;
      float vt = c0 * c0 + ((cl < 4) ? c1 * c1 : 0.f);
      vt += __shfl_xor(vt, 1, 16);
      vt += __shfl_xor(vt, 2, 16);
      vt += __shfl_xor(vt, 4, 16);
      vt += __shfl_xor(vt, 8, 16);
      float rs = rsqrtf(vt * (1.0f / 20.0f) + EPS);
      const long grow = wrbase + rrow;
      if (rrow < 63 && grow < total_rows) {
        Out[grow * 20 + cl] = c0 * rs * gg0 + bb0;
        if (cl < 4) Out[grow * 20 + 16 + cl] = c1 * rs * gg1 + bb1;
      }
    }
  }
}

extern "C" void kernel_launch(void* const* d_in, const int* in_sizes, int n_in,
                              void* d_out, int out_size, void* d_ws, size_t ws_size,
                              hipStream_t stream) {
  const float* X  = (const float*)d_in[0];
  const float* Wq = (const float*)d_in[1];
  const float* bq = (const float*)d_in[2];
  const float* Wk = (const float*)d_in[3];
  const float* bk = (const float*)d_in[4];
  const float* Wv = (const float*)d_in[5];
  const float* bv = (const float*)d_in[6];
  const float* Wo = (const float*)d_in[7];
  const float* bo = (const float*)d_in[8];
  const float* g1 = (const float*)d_in[9];
  const float* b1 = (const float*)d_in[10];
  const float* W1 = (const float*)d_in[11];
  const float* W2 = (const float*)d_in[12];
  const float* g2 = (const float*)d_in[13];
  const float* b2 = (const float*)d_in[14];
  float* Out = (float*)d_out;
  float* ws = (float*)d_ws;

  prep_kernel<<<144, 256, 0, stream>>>(Wq, Wk, Wv, Wo, W1, W2, bq, bk, bv, bo, ws);

  int nblocks = (B_TOT + 27) / 28;  // 4 waves/block * 7 batch elems/wave
  encoder_kernel<<<nblocks, 256, 0, stream>>>(X, ws, g1, b1, g2, b2, Out);
}

// Round 8
// 158.980 us; speedup vs baseline: 1.2316x; 1.2316x over previous
//
#include <hip/hip_runtime.h>
#include <hip/hip_bf16.h>

#define B_TOT 65536
#define S 9
#define D 20
#define DFF 512
#define EPS 1e-5f

typedef short bf16x8 __attribute__((ext_vector_type(8)));
typedef float f32x4 __attribute__((ext_vector_type(4)));

// ws layout (identical to round 7 — numerically verified):
//   PQKV  [4ct][64][8] bf16 @ short 0     : A-frags of [Wq|Wk|Wv]^T
//   PWOA  [2ct][64][8] bf16 @ short 2048  : A-frags of Wo^T
//   BQKV  f32[64]  @ float 1536           : bq|bk|bv concat (pad 0)
//   BO4   f32[64]  @ float 1600           : bo padded
//   PA1   [32frag][64][8] @ short 3328    : W1 A-frags, PERMUTED
//   PB2   [32frag][64][8] @ short 19712   : W2 B-frags
#define SH_PQKV 0
#define SH_PWOA 2048
#define FL_BQKV 1536
#define FL_BO4 1600
#define SH_PA1 3328
#define SH_PB2 19712
#define PREP_TOTAL (2048 + 1024 + 128 + 16384 + 16384)

__device__ __forceinline__ unsigned short f2bf(float f) {
  union { __hip_bfloat16 h; unsigned short u; } v;
  v.h = __float2bfloat16(f);
  return v.u;
}
__device__ __forceinline__ float bf2f(unsigned short h) {
  union { unsigned u; float f; } v; v.u = ((unsigned)h) << 16; return v.f;
}
__device__ __forceinline__ unsigned cvt2(float a, float b) {
  union { __hip_bfloat162 h; unsigned u; } v;
  v.h = __float22bfloat162_rn(make_float2(a, b));
  return v.u;
}
__device__ __forceinline__ void unpk(unsigned u, float& lo, float& hi) {
  union { unsigned v; float f; } a, b;
  a.v = u << 16; b.v = u & 0xffff0000u;
  lo = a.f; hi = b.f;
}
// 40B row as 5x uint2 (8B-aligned rows; works for 40/88-stride regions)
__device__ __forceinline__ void unpack20_u2(const char* p, float* o) {
  uint2 r0 = *(const uint2*)p, r1 = *(const uint2*)(p + 8), r2 = *(const uint2*)(p + 16);
  uint2 r3 = *(const uint2*)(p + 24), r4 = *(const uint2*)(p + 32);
  unpk(r0.x, o[0], o[1]); unpk(r0.y, o[2], o[3]);
  unpk(r1.x, o[4], o[5]); unpk(r1.y, o[6], o[7]);
  unpk(r2.x, o[8], o[9]); unpk(r2.y, o[10], o[11]);
  unpk(r3.x, o[12], o[13]); unpk(r3.y, o[14], o[15]);
  unpk(r4.x, o[16], o[17]); unpk(r4.y, o[18], o[19]);
}

__global__ void prep_kernel(const float* __restrict__ Wq, const float* __restrict__ Wk,
                            const float* __restrict__ Wv, const float* __restrict__ Wo,
                            const float* __restrict__ W1, const float* __restrict__ W2,
                            const float* __restrict__ bq, const float* __restrict__ bk,
                            const float* __restrict__ bv, const float* __restrict__ bo,
                            float* __restrict__ wsf) {
  int stride = gridDim.x * blockDim.x;
  unsigned short* P = (unsigned short*)wsf;
  for (int i = blockIdx.x * blockDim.x + threadIdx.x; i < PREP_TOTAL; i += stride) {
    if (i < 2048) {
      int ct = i >> 9, rem = i & 511, l = rem >> 3, jj = rem & 7;
      int g = l >> 4, cl = l & 15;
      int j = ct * 16 + cl, d = 8 * g + jj;
      unsigned short v = 0;
      if (d < 20 && j < 60) {
        int mat = j / 20, jc = j % 20;
        const float* Wsrc = (mat == 0) ? Wq : (mat == 1) ? Wk : Wv;
        v = f2bf(Wsrc[d * 20 + jc]);
      }
      P[SH_PQKV + i] = v;
    } else if (i < 3072) {
      int p = i - 2048;
      int ct = p >> 9, rem = p & 511, l = rem >> 3, jj = rem & 7;
      int g = l >> 4, cl = l & 15;
      int j = ct * 16 + cl, d = 8 * g + jj;
      P[SH_PWOA + p] = (d < 20 && j < 20) ? f2bf(Wo[d * 20 + j]) : (unsigned short)0;
    } else if (i < 3200) {
      int j = i - 3072;  // 0..127
      float v = 0.f;
      if (j < 20) v = bq[j];
      else if (j < 40) v = bk[j - 20];
      else if (j < 60) v = bv[j - 40];
      else if (j >= 64 && j < 84) v = bo[j - 64];
      wsf[FL_BQKV + j] = v;
    } else if (i < 3200 + 16384) {
      int j = i - 3200;
      int frag = j >> 9, rem = j & 511;
      int l = rem >> 3, jj = rem & 7;
      int p = frag & 1, q2 = (frag >> 1) & 3, ch = frag >> 3;
      int g2 = l >> 4, cl2 = l & 15;
      int k = 8 * g2 + jj;
      int f = ch * 128 + q2 * 32 + 8 * (cl2 >> 2) + 4 * p + (cl2 & 3);
      P[SH_PA1 + j] = (k < 20) ? f2bf(W1[k * DFF + f]) : (unsigned short)0;
    } else {
      int j = i - (3200 + 16384);
      int pair = j >> 9, rem = j & 511;
      int l = rem >> 3, jj = rem & 7;
      int g = l >> 4, cl = l & 15;
      int kk = pair >> 1, cc = pair & 1;
      int kg = kk * 32 + 8 * g + jj;
      int d = cc * 16 + cl;
      P[SH_PB2 + j] = (d < 20) ? f2bf(W2[kg * 20 + d]) : (unsigned short)0;
    }
  }
}

// Per-wave LDS slab 13312 B, wave-private (NO __syncthreads):
//   RA @0     stride 80, 64 rows (16B-aligned): Xstage (data 0..39, zeros 40..63) -> Y
//   RB @5120  stride 88, 64 rows: k@0..39, v@48..87 (uint2 access)
//             -> overlay: merged/ao stride 80 (data 0..39, zeros 40..63)
//   RC @10752 stride 40, 64 rows: q (uint2 access)
// Strides 80/88/40 (20/22/10 dw) break the 64B {0,16}-bank pathology (round-7's 10M conflicts).
// All overlays fenced; all strides linear (round-4 lesson).
#define SLAB_BYTES 13312
#define RA 0
#define RB 5120
#define RC 10752

#define FENCE() asm volatile("" ::: "memory")

__global__ __launch_bounds__(256, 3) void encoder_kernel(
    const float* __restrict__ X, const float* __restrict__ ws,
    const float* __restrict__ g1, const float* __restrict__ b1,
    const float* __restrict__ g2, const float* __restrict__ b2,
    float* __restrict__ Out) {
  __shared__ __align__(16) char smem[4 * SLAB_BYTES];

  const unsigned short* P16 = (const unsigned short*)ws;
  const unsigned short* PQKV = P16 + SH_PQKV;
  const unsigned short* PWOA = P16 + SH_PWOA;
  const float* BQKV = ws + FL_BQKV;
  const float* BO4 = ws + FL_BO4;
  const unsigned short* PA1 = P16 + SH_PA1;
  const unsigned short* PB2 = P16 + SH_PB2;

  const int tid = threadIdx.x;
  const int wv = tid >> 6;
  const int lane = tid & 63;
  const int bl = lane / 9;     // 0..7 (7 == pad lane 63)
  const int s = lane - bl * 9;
  const long wb = (long)blockIdx.x * 4 + wv;
  const long bb = wb * 7 + bl;
  const bool active = (bl < 7) && (bb < B_TOT);

  char* slab = smem + wv * SLAB_BYTES;
  const int cl = lane & 15;
  const int g = lane >> 4;
  const f32x4 zero4 = {0.f, 0.f, 0.f, 0.f};

  // ---------------- stage X bf16 rows (zeros for inactive); x NOT kept in regs
  {
    float x[20];
    if (active) {
      const float4* xr = (const float4*)(X + bb * (S * D) + s * D);
#pragma unroll
      for (int i = 0; i < 5; ++i) {
        float4 t = xr[i];
        x[4 * i + 0] = t.x; x[4 * i + 1] = t.y; x[4 * i + 2] = t.z; x[4 * i + 3] = t.w;
      }
    } else {
#pragma unroll
      for (int i = 0; i < 20; ++i) x[i] = 0.f;
    }
    unsigned u[10];
#pragma unroll
    for (int i = 0; i < 10; ++i) u[i] = cvt2(x[2 * i], x[2 * i + 1]);
    uint4* dst = (uint4*)(slab + RA + lane * 80);
    dst[0] = make_uint4(u[0], u[1], u[2], u[3]);
    dst[1] = make_uint4(u[4], u[5], u[6], u[7]);
    dst[2] = make_uint4(u[8], u[9], 0u, 0u);
    dst[3] = make_uint4(0u, 0u, 0u, 0u);
  }
  FENCE();

  // ---------------- X B-frags ------------------------------------------------
  bf16x8 xfB[4];
#pragma unroll
  for (int rtc = 0; rtc < 4; ++rtc)
    xfB[rtc] = *(const bf16x8*)(slab + RA + (rtc * 16 + cl) * 80 + g * 16);
  FENCE();

  // ---------------- QKV MFMA (swapped), packed quad scatter ------------------
#pragma unroll
  for (int ct = 0; ct < 4; ++ct) {
    bf16x8 wf = *(const bf16x8*)(PQKV + (size_t)(ct * 64 + lane) * 8);
    float4 bq4 = *(const float4*)(BQKV + ct * 16 + 4 * g);
    const int qd = ct * 4 + g;
    const int mat = (qd >= 10) ? 2 : ((qd >= 5) ? 1 : 0);
    const int jc4 = qd - 5 * mat;
    const bool qv = qd < 15;
#pragma unroll
    for (int rtc = 0; rtc < 4; ++rtc) {
      f32x4 d = __builtin_amdgcn_mfma_f32_16x16x32_bf16(wf, xfB[rtc], zero4, 0, 0, 0);
      if (qv) {
        const int row = rtc * 16 + cl;
        unsigned u0 = cvt2(d[0] + bq4.x, d[1] + bq4.y);
        unsigned u1 = cvt2(d[2] + bq4.z, d[3] + bq4.w);
        char* p = (mat == 0) ? (slab + RC + row * 40 + jc4 * 8)
                             : (slab + RB + row * 88 + ((mat == 2) ? 48 : 0) + jc4 * 8);
        *(uint2*)p = make_uint2(u0, u1);
      }
    }
  }
  FENCE();

  // ---------------- attention (per-lane row) ---------------------------------
  float ctx[20];
  if (active) {
    float q[20];
    unpack20_u2(slab + RC + lane * 40, q);
    float sc[4][9];
#pragma unroll
    for (int t = 0; t < 9; ++t) {
      float kt[20];
      unpack20_u2(slab + RB + (bl * 9 + t) * 88, kt);
#pragma unroll
      for (int h = 0; h < 4; ++h) {
        float d0 = q[h * 5 + 0] * kt[h * 5 + 0] + q[h * 5 + 1] * kt[h * 5 + 1];
        float d1 = q[h * 5 + 2] * kt[h * 5 + 2] + q[h * 5 + 3] * kt[h * 5 + 3];
        sc[h][t] = d0 + d1 + q[h * 5 + 4] * kt[h * 5 + 4];
      }
    }
    float inv4[4];
#pragma unroll
    for (int h = 0; h < 4; ++h) {
      float mx = sc[h][0];
#pragma unroll
      for (int t = 1; t < 9; ++t) mx = fmaxf(mx, sc[h][t]);
      float sum = 0.f;
#pragma unroll
      for (int t = 0; t < 9; ++t) {
        sc[h][t] = __expf((sc[h][t] - mx) * (1.0f / 3.0f));
        sum += sc[h][t];
      }
      inv4[h] = 1.0f / sum;
    }
#pragma unroll
    for (int j = 0; j < 20; ++j) ctx[j] = 0.f;
#pragma unroll
    for (int t = 0; t < 9; ++t) {
      float vt[20];
      unpack20_u2(slab + RB + (bl * 9 + t) * 88 + 48, vt);
#pragma unroll
      for (int h = 0; h < 4; ++h)
#pragma unroll
        for (int dh = 0; dh < 5; ++dh)
          ctx[h * 5 + dh] += sc[h][t] * vt[h * 5 + dh];
    }
#pragma unroll
    for (int h = 0; h < 4; ++h)
#pragma unroll
      for (int dh = 0; dh < 5; ++dh)
        ctx[h * 5 + dh] *= inv4[h];
  }
  FENCE();  // k/v reads done before merged overlay of RB

  // ---------------- merged-ctx scatter (transpose quirk), stride 80 in RB ----
  if (active) {
    int m = s;  // merged linear index m = 9*w + s, w = 5h+dh
#pragma unroll
    for (int w = 0; w < 20; ++w) {
      int row = (m * 3277) >> 16;  // m/20 (m < 180)
      int col = m - 20 * row;
      *(unsigned short*)(slab + RB + (bl * 9 + row) * 80 + col * 2) = f2bf(ctx[w]);
      m += 9;
    }
  } else {
    // define this lane's merged row data (rows not covered by active scatter)
    *(uint4*)(slab + RB + lane * 80) = make_uint4(0u, 0u, 0u, 0u);
    *(uint4*)(slab + RB + lane * 80 + 16) = make_uint4(0u, 0u, 0u, 0u);
    *(uint2*)(slab + RB + lane * 80 + 32) = make_uint2(0u, 0u);
  }
  // zero-pad merged cols 20..31 (every lane owns row `lane`)
  *(uint2*)(slab + RB + lane * 80 + 40) = make_uint2(0u, 0u);
  *(uint4*)(slab + RB + lane * 80 + 48) = make_uint4(0u, 0u, 0u, 0u);
  FENCE();

  // ---------------- Wo MFMA (swapped), quad scatter ao -> RB overlay ---------
  bf16x8 mfB[4];
#pragma unroll
  for (int rtc = 0; rtc < 4; ++rtc)
    mfB[rtc] = *(const bf16x8*)(slab + RB + (rtc * 16 + cl) * 80 + g * 16);
  FENCE();  // merged consumed before ao overlay
#pragma unroll
  for (int ct = 0; ct < 2; ++ct) {
    bf16x8 wof = *(const bf16x8*)(PWOA + (size_t)(ct * 64 + lane) * 8);
    float4 bo4 = *(const float4*)(BO4 + ct * 16 + 4 * g);
    const int qd = ct * 4 + g;
    const bool qv = qd < 5;
#pragma unroll
    for (int rtc = 0; rtc < 4; ++rtc) {
      f32x4 d = __builtin_amdgcn_mfma_f32_16x16x32_bf16(wof, mfB[rtc], zero4, 0, 0, 0);
      if (qv) {
        const int row = rtc * 16 + cl;
        unsigned u0 = cvt2(d[0] + bo4.x, d[1] + bo4.y);
        unsigned u1 = cvt2(d[2] + bo4.z, d[3] + bo4.w);
        *(uint2*)(slab + RB + row * 80 + qd * 8) = make_uint2(u0, u1);
      }
    }
  }
  FENCE();

  // ---------------- LN1 (x re-read from staged bf16 X rows) ------------------
  float y[20];
  if (active) {
    float ao[20], xr[20];
    unpack20_u2(slab + RB + lane * 80, ao);
    unpack20_u2(slab + RA + lane * 80, xr);
    float z[20];
#pragma unroll
    for (int d = 0; d < 20; ++d) z[d] = ao[d] + xr[d];
    float t0 = 0.f;
#pragma unroll
    for (int d = 0; d < 20; ++d) t0 += z[d];
    float mean = t0 * (1.0f / 20.0f);
    float var = 0.f;
#pragma unroll
    for (int d = 0; d < 20; ++d) { z[d] -= mean; var += z[d] * z[d]; }
    float rs = rsqrtf(var * (1.0f / 20.0f) + EPS);
#pragma unroll
    for (int d = 0; d < 20; ++d) y[d] = z[d] * rs * g1[d] + b1[d];
  } else {
#pragma unroll
    for (int d = 0; d < 20; ++d) y[d] = 0.f;
  }
  FENCE();  // X reads done before Y overlay of RA

  // ---------------- stage Y bf16 rows ----------------------------------------
  {
    unsigned u[10];
#pragma unroll
    for (int i = 0; i < 10; ++i) u[i] = cvt2(y[2 * i], y[2 * i + 1]);
    uint4* dst = (uint4*)(slab + RA + lane * 80);
    dst[0] = make_uint4(u[0], u[1], u[2], u[3]);
    dst[1] = make_uint4(u[4], u[5], u[6], u[7]);
    dst[2] = make_uint4(u[8], u[9], 0u, 0u);
    dst[3] = make_uint4(0u, 0u, 0u, 0u);
  }
  FENCE();

  // ---------------- FFN via MFMA (register-resident H, verified flow) --------
  bf16x8 ytf[4];
#pragma unroll
  for (int rt = 0; rt < 4; ++rt)
    ytf[rt] = *(const bf16x8*)(slab + RA + (rt * 16 + cl) * 80 + g * 16);

  f32x4 acc[4][2];
#pragma unroll
  for (int rt = 0; rt < 4; ++rt) { acc[rt][0] = zero4; acc[rt][1] = zero4; }

  for (int ch = 0; ch < 4; ++ch) {
#pragma unroll
    for (int q2 = 0; q2 < 4; ++q2) {
      const int fb = ch * 8 + q2 * 2;
      bf16x8 aw0 = *(const bf16x8*)(PA1 + (size_t)(fb * 64 + lane) * 8);
      bf16x8 aw1 = *(const bf16x8*)(PA1 + (size_t)((fb + 1) * 64 + lane) * 8);
      bf16x8 bw0 = *(const bf16x8*)(PB2 + (size_t)(fb * 64 + lane) * 8);
      bf16x8 bw1 = *(const bf16x8*)(PB2 + (size_t)((fb + 1) * 64 + lane) * 8);
#pragma unroll
      for (int rt = 0; rt < 4; ++rt) {
        f32x4 d0 = __builtin_amdgcn_mfma_f32_16x16x32_bf16(aw0, ytf[rt], zero4, 0, 0, 0);
        f32x4 d1 = __builtin_amdgcn_mfma_f32_16x16x32_bf16(aw1, ytf[rt], zero4, 0, 0, 0);
        union { bf16x8 v; unsigned uu[4]; } af;
        af.uu[0] = cvt2(fmaxf(d0[0], 0.f), fmaxf(d0[1], 0.f));
        af.uu[1] = cvt2(fmaxf(d0[2], 0.f), fmaxf(d0[3], 0.f));
        af.uu[2] = cvt2(fmaxf(d1[0], 0.f), fmaxf(d1[1], 0.f));
        af.uu[3] = cvt2(fmaxf(d1[2], 0.f), fmaxf(d1[3], 0.f));
        acc[rt][0] = __builtin_amdgcn_mfma_f32_16x16x32_bf16(af.v, bw0, acc[rt][0], 0, 0, 0);
        acc[rt][1] = __builtin_amdgcn_mfma_f32_16x16x32_bf16(af.v, bw1, acc[rt][1], 0, 0, 0);
      }
    }
  }

  // ---------------- LN2 in fragment space + store ----------------------------
  const float gg0 = g2[cl], bb0 = b2[cl];
  const float gg1 = (cl < 4) ? g2[16 + cl] : 0.f;
  const float bb1 = (cl < 4) ? b2[16 + cl] : 0.f;
  const long wrbase = wb * 63;
  const long total_rows = (long)B_TOT * S;

#pragma unroll
  for (int rt = 0; rt < 4; ++rt) {
#pragma unroll
    for (int r = 0; r < 4; ++r) {
      const int rrow = rt * 16 + 4 * g + r;
      float y0 = bf2f(*(const unsigned short*)(slab + RA + rrow * 80 + cl * 2));
      float y1 = (cl < 4) ? bf2f(*(const unsigned short*)(slab + RA + rrow * 80 + 32 + cl * 2)) : 0.f;
      float z0 = acc[rt][0][r] + y0;
      float z1 = acc[rt][1][r] + y1;
      float t = z0 + ((cl < 4) ? z1 : 0.f);
      t += __shfl_xor(t, 1, 16);
      t += __shfl_xor(t, 2, 16);
      t += __shfl_xor(t, 4, 16);
      t += __shfl_xor(t, 8, 16);
      float mean = t * (1.0f / 20.0f);
      float c0 = z0 - mean, c1 = z1 - mean;
      float vt = c0 * c0 + ((cl < 4) ? c1 * c1 : 0.f);
      vt += __shfl_xor(vt, 1, 16);
      vt += __shfl_xor(vt, 2, 16);
      vt += __shfl_xor(vt, 4, 16);
      vt += __shfl_xor(vt, 8, 16);
      float rs = rsqrtf(vt * (1.0f / 20.0f) + EPS);
      const long grow = wrbase + rrow;
      if (rrow < 63 && grow < total_rows) {
        Out[grow * 20 + cl] = c0 * rs * gg0 + bb0;
        if (cl < 4) Out[grow * 20 + 16 + cl] = c1 * rs * gg1 + bb1;
      }
    }
  }
}

extern "C" void kernel_launch(void* const* d_in, const int* in_sizes, int n_in,
                              void* d_out, int out_size, void* d_ws, size_t ws_size,
                              hipStream_t stream) {
  const float* X  = (const float*)d_in[0];
  const float* Wq = (const float*)d_in[1];
  const float* bq = (const float*)d_in[2];
  const float* Wk = (const float*)d_in[3];
  const float* bk = (const float*)d_in[4];
  const float* Wv = (const float*)d_in[5];
  const float* bv = (const float*)d_in[6];
  const float* Wo = (const float*)d_in[7];
  const float* bo = (const float*)d_in[8];
  const float* g1 = (const float*)d_in[9];
  const float* b1 = (const float*)d_in[10];
  const float* W1 = (const float*)d_in[11];
  const float* W2 = (const float*)d_in[12];
  const float* g2 = (const float*)d_in[13];
  const float* b2 = (const float*)d_in[14];
  float* Out = (float*)d_out;
  float* ws = (float*)d_ws;

  prep_kernel<<<144, 256, 0, stream>>>(Wq, Wk, Wv, Wo, W1, W2, bq, bk, bv, bo, ws);

  int nblocks = (B_TOT + 27) / 28;  // 4 waves/block * 7 batch elems/wave
  encoder_kernel<<<nblocks, 256, 0, stream>>>(X, ws, g1, b1, g2, b2, Out);
}

// Round 9
// 124.380 us; speedup vs baseline: 1.5742x; 1.2782x over previous
//
#include <hip/hip_runtime.h>
#include <hip/hip_bf16.h>

#define B_TOT 65536
#define S 9
#define D 20
#define DFF 512
#define EPS 1e-5f

typedef short bf16x8 __attribute__((ext_vector_type(8)));
typedef float f32x4 __attribute__((ext_vector_type(4)));

// ws layout (identical to round 7/8 — numerically verified):
//   PQKV  [4ct][64][8] bf16 @ short 0     : A-frags of [Wq|Wk|Wv]^T
//   PWOA  [2ct][64][8] bf16 @ short 2048  : A-frags of Wo^T
//   BQKV  f32[64]  @ float 1536           : bq|bk|bv concat (pad 0)
//   BO4   f32[64]  @ float 1600           : bo padded
//   PA1   [32frag][64][8] @ short 3328    : W1 A-frags, PERMUTED
//   PB2   [32frag][64][8] @ short 19712   : W2 B-frags
#define SH_PQKV 0
#define SH_PWOA 2048
#define FL_BQKV 1536
#define FL_BO4 1600
#define SH_PA1 3328
#define SH_PB2 19712
#define PREP_TOTAL (2048 + 1024 + 128 + 16384 + 16384)

__device__ __forceinline__ unsigned short f2bf(float f) {
  union { __hip_bfloat16 h; unsigned short u; } v;
  v.h = __float2bfloat16(f);
  return v.u;
}
__device__ __forceinline__ float bf2f(unsigned short h) {
  union { unsigned u; float f; } v; v.u = ((unsigned)h) << 16; return v.f;
}
__device__ __forceinline__ unsigned cvt2(float a, float b) {
  union { __hip_bfloat162 h; unsigned u; } v;
  v.h = __float22bfloat162_rn(make_float2(a, b));
  return v.u;
}
__device__ __forceinline__ void unpk(unsigned u, float& lo, float& hi) {
  union { unsigned v; float f; } a, b;
  a.v = u << 16; b.v = u & 0xffff0000u;
  lo = a.f; hi = b.f;
}
// 40B row as 5x uint2 (8B-aligned rows; works for 40/88-stride regions)
__device__ __forceinline__ void unpack20_u2(const char* p, float* o) {
  uint2 r0 = *(const uint2*)p, r1 = *(const uint2*)(p + 8), r2 = *(const uint2*)(p + 16);
  uint2 r3 = *(const uint2*)(p + 24), r4 = *(const uint2*)(p + 32);
  unpk(r0.x, o[0], o[1]); unpk(r0.y, o[2], o[3]);
  unpk(r1.x, o[4], o[5]); unpk(r1.y, o[6], o[7]);
  unpk(r2.x, o[8], o[9]); unpk(r2.y, o[10], o[11]);
  unpk(r3.x, o[12], o[13]); unpk(r3.y, o[14], o[15]);
  unpk(r4.x, o[16], o[17]); unpk(r4.y, o[18], o[19]);
}

__global__ void prep_kernel(const float* __restrict__ Wq, const float* __restrict__ Wk,
                            const float* __restrict__ Wv, const float* __restrict__ Wo,
                            const float* __restrict__ W1, const float* __restrict__ W2,
                            const float* __restrict__ bq, const float* __restrict__ bk,
                            const float* __restrict__ bv, const float* __restrict__ bo,
                            float* __restrict__ wsf) {
  int stride = gridDim.x * blockDim.x;
  unsigned short* P = (unsigned short*)wsf;
  for (int i = blockIdx.x * blockDim.x + threadIdx.x; i < PREP_TOTAL; i += stride) {
    if (i < 2048) {
      int ct = i >> 9, rem = i & 511, l = rem >> 3, jj = rem & 7;
      int g = l >> 4, cl = l & 15;
      int j = ct * 16 + cl, d = 8 * g + jj;
      unsigned short v = 0;
      if (d < 20 && j < 60) {
        int mat = j / 20, jc = j % 20;
        const float* Wsrc = (mat == 0) ? Wq : (mat == 1) ? Wk : Wv;
        v = f2bf(Wsrc[d * 20 + jc]);
      }
      P[SH_PQKV + i] = v;
    } else if (i < 3072) {
      int p = i - 2048;
      int ct = p >> 9, rem = p & 511, l = rem >> 3, jj = rem & 7;
      int g = l >> 4, cl = l & 15;
      int j = ct * 16 + cl, d = 8 * g + jj;
      P[SH_PWOA + p] = (d < 20 && j < 20) ? f2bf(Wo[d * 20 + j]) : (unsigned short)0;
    } else if (i < 3200) {
      int j = i - 3072;  // 0..127
      float v = 0.f;
      if (j < 20) v = bq[j];
      else if (j < 40) v = bk[j - 20];
      else if (j < 60) v = bv[j - 40];
      else if (j >= 64 && j < 84) v = bo[j - 64];
      wsf[FL_BQKV + j] = v;
    } else if (i < 3200 + 16384) {
      int j = i - 3200;
      int frag = j >> 9, rem = j & 511;
      int l = rem >> 3, jj = rem & 7;
      int p = frag & 1, q2 = (frag >> 1) & 3, ch = frag >> 3;
      int g2 = l >> 4, cl2 = l & 15;
      int k = 8 * g2 + jj;
      int f = ch * 128 + q2 * 32 + 8 * (cl2 >> 2) + 4 * p + (cl2 & 3);
      P[SH_PA1 + j] = (k < 20) ? f2bf(W1[k * DFF + f]) : (unsigned short)0;
    } else {
      int j = i - (3200 + 16384);
      int pair = j >> 9, rem = j & 511;
      int l = rem >> 3, jj = rem & 7;
      int g = l >> 4, cl = l & 15;
      int kk = pair >> 1, cc = pair & 1;
      int kg = kk * 32 + 8 * g + jj;
      int d = cc * 16 + cl;
      P[SH_PB2 + j] = (d < 20) ? f2bf(W2[kg * 20 + d]) : (unsigned short)0;
    }
  }
}

// Per-wave LDS slab 13312 B, wave-private (NO __syncthreads):
//   RA @0     stride 80, 64 rows (16B-aligned): Xstage (data 0..39, zeros 40..63) -> Y
//   RB @5120  stride 88, 64 rows: k@0..39, v@48..87 (uint2 access)
//             -> overlay: merged/ao stride 80 (data 0..39, zeros 40..63)
//   RC @10752 stride 40, 64 rows: q (uint2 access)
// Strides 80/88/40 break the 64B {0,16}-bank pathology (round-7's 10M conflicts).
// All overlays fenced; all strides linear (round-4 lesson).
#define SLAB_BYTES 13312
#define RA 0
#define RB 5120
#define RC 10752

#define FENCE() asm volatile("" ::: "memory")

// launch_bounds(256,2): 256-reg cap on the UNIFIED VGPR+AGPR file.
// Round-8 evidence: (256,3)=170 cap forced arch/acc split 84+~84 -> ~150MB of
// scratch spill traffic. Actual need ~160 regs; runtime occupancy stays
// LDS-limited at 3 blocks/CU either way. Do NOT tighten this.
__global__ __launch_bounds__(256, 2) void encoder_kernel(
    const float* __restrict__ X, const float* __restrict__ ws,
    const float* __restrict__ g1, const float* __restrict__ b1,
    const float* __restrict__ g2, const float* __restrict__ b2,
    float* __restrict__ Out) {
  __shared__ __align__(16) char smem[4 * SLAB_BYTES];

  const unsigned short* P16 = (const unsigned short*)ws;
  const unsigned short* PQKV = P16 + SH_PQKV;
  const unsigned short* PWOA = P16 + SH_PWOA;
  const float* BQKV = ws + FL_BQKV;
  const float* BO4 = ws + FL_BO4;
  const unsigned short* PA1 = P16 + SH_PA1;
  const unsigned short* PB2 = P16 + SH_PB2;

  const int tid = threadIdx.x;
  const int wv = tid >> 6;
  const int lane = tid & 63;
  const int bl = lane / 9;     // 0..7 (7 == pad lane 63)
  const int s = lane - bl * 9;
  const long wb = (long)blockIdx.x * 4 + wv;
  const long bb = wb * 7 + bl;
  const bool active = (bl < 7) && (bb < B_TOT);

  char* slab = smem + wv * SLAB_BYTES;
  const int cl = lane & 15;
  const int g = lane >> 4;
  const f32x4 zero4 = {0.f, 0.f, 0.f, 0.f};

  // ---------------- stage X bf16 rows (zeros for inactive); x NOT kept in regs
  {
    float x[20];
    if (active) {
      const float4* xr = (const float4*)(X + bb * (S * D) + s * D);
#pragma unroll
      for (int i = 0; i < 5; ++i) {
        float4 t = xr[i];
        x[4 * i + 0] = t.x; x[4 * i + 1] = t.y; x[4 * i + 2] = t.z; x[4 * i + 3] = t.w;
      }
    } else {
#pragma unroll
      for (int i = 0; i < 20; ++i) x[i] = 0.f;
    }
    unsigned u[10];
#pragma unroll
    for (int i = 0; i < 10; ++i) u[i] = cvt2(x[2 * i], x[2 * i + 1]);
    uint4* dst = (uint4*)(slab + RA + lane * 80);
    dst[0] = make_uint4(u[0], u[1], u[2], u[3]);
    dst[1] = make_uint4(u[4], u[5], u[6], u[7]);
    dst[2] = make_uint4(u[8], u[9], 0u, 0u);
    dst[3] = make_uint4(0u, 0u, 0u, 0u);
  }
  FENCE();

  // ---------------- X B-frags ------------------------------------------------
  bf16x8 xfB[4];
#pragma unroll
  for (int rtc = 0; rtc < 4; ++rtc)
    xfB[rtc] = *(const bf16x8*)(slab + RA + (rtc * 16 + cl) * 80 + g * 16);
  FENCE();

  // ---------------- QKV MFMA (swapped), packed quad scatter ------------------
#pragma unroll
  for (int ct = 0; ct < 4; ++ct) {
    bf16x8 wf = *(const bf16x8*)(PQKV + (size_t)(ct * 64 + lane) * 8);
    float4 bq4 = *(const float4*)(BQKV + ct * 16 + 4 * g);
    const int qd = ct * 4 + g;
    const int mat = (qd >= 10) ? 2 : ((qd >= 5) ? 1 : 0);
    const int jc4 = qd - 5 * mat;
    const bool qv = qd < 15;
#pragma unroll
    for (int rtc = 0; rtc < 4; ++rtc) {
      f32x4 d = __builtin_amdgcn_mfma_f32_16x16x32_bf16(wf, xfB[rtc], zero4, 0, 0, 0);
      if (qv) {
        const int row = rtc * 16 + cl;
        unsigned u0 = cvt2(d[0] + bq4.x, d[1] + bq4.y);
        unsigned u1 = cvt2(d[2] + bq4.z, d[3] + bq4.w);
        char* p = (mat == 0) ? (slab + RC + row * 40 + jc4 * 8)
                             : (slab + RB + row * 88 + ((mat == 2) ? 48 : 0) + jc4 * 8);
        *(uint2*)p = make_uint2(u0, u1);
      }
    }
  }
  FENCE();

  // ---------------- attention (per-lane row) ---------------------------------
  float ctx[20];
  if (active) {
    float q[20];
    unpack20_u2(slab + RC + lane * 40, q);
    float sc[4][9];
#pragma unroll
    for (int t = 0; t < 9; ++t) {
      float kt[20];
      unpack20_u2(slab + RB + (bl * 9 + t) * 88, kt);
#pragma unroll
      for (int h = 0; h < 4; ++h) {
        float d0 = q[h * 5 + 0] * kt[h * 5 + 0] + q[h * 5 + 1] * kt[h * 5 + 1];
        float d1 = q[h * 5 + 2] * kt[h * 5 + 2] + q[h * 5 + 3] * kt[h * 5 + 3];
        sc[h][t] = d0 + d1 + q[h * 5 + 4] * kt[h * 5 + 4];
      }
    }
    float inv4[4];
#pragma unroll
    for (int h = 0; h < 4; ++h) {
      float mx = sc[h][0];
#pragma unroll
      for (int t = 1; t < 9; ++t) mx = fmaxf(mx, sc[h][t]);
      float sum = 0.f;
#pragma unroll
      for (int t = 0; t < 9; ++t) {
        sc[h][t] = __expf((sc[h][t] - mx) * (1.0f / 3.0f));
        sum += sc[h][t];
      }
      inv4[h] = 1.0f / sum;
    }
#pragma unroll
    for (int j = 0; j < 20; ++j) ctx[j] = 0.f;
#pragma unroll
    for (int t = 0; t < 9; ++t) {
      float vt[20];
      unpack20_u2(slab + RB + (bl * 9 + t) * 88 + 48, vt);
#pragma unroll
      for (int h = 0; h < 4; ++h)
#pragma unroll
        for (int dh = 0; dh < 5; ++dh)
          ctx[h * 5 + dh] += sc[h][t] * vt[h * 5 + dh];
    }
#pragma unroll
    for (int h = 0; h < 4; ++h)
#pragma unroll
      for (int dh = 0; dh < 5; ++dh)
        ctx[h * 5 + dh] *= inv4[h];
  }
  FENCE();  // k/v reads done before merged overlay of RB

  // ---------------- merged-ctx scatter (transpose quirk), stride 80 in RB ----
  if (active) {
    int m = s;  // merged linear index m = 9*w + s, w = 5h+dh
#pragma unroll
    for (int w = 0; w < 20; ++w) {
      int row = (m * 3277) >> 16;  // m/20 (m < 180)
      int col = m - 20 * row;
      *(unsigned short*)(slab + RB + (bl * 9 + row) * 80 + col * 2) = f2bf(ctx[w]);
      m += 9;
    }
  } else {
    // define this lane's merged row data (rows not covered by active scatter)
    *(uint4*)(slab + RB + lane * 80) = make_uint4(0u, 0u, 0u, 0u);
    *(uint4*)(slab + RB + lane * 80 + 16) = make_uint4(0u, 0u, 0u, 0u);
    *(uint2*)(slab + RB + lane * 80 + 32) = make_uint2(0u, 0u);
  }
  // zero-pad merged cols 20..31 (every lane owns row `lane`)
  *(uint2*)(slab + RB + lane * 80 + 40) = make_uint2(0u, 0u);
  *(uint4*)(slab + RB + lane * 80 + 48) = make_uint4(0u, 0u, 0u, 0u);
  FENCE();

  // ---------------- Wo MFMA (swapped), quad scatter ao -> RB overlay ---------
  bf16x8 mfB[4];
#pragma unroll
  for (int rtc = 0; rtc < 4; ++rtc)
    mfB[rtc] = *(const bf16x8*)(slab + RB + (rtc * 16 + cl) * 80 + g * 16);
  FENCE();  // merged consumed before ao overlay
#pragma unroll
  for (int ct = 0; ct < 2; ++ct) {
    bf16x8 wof = *(const bf16x8*)(PWOA + (size_t)(ct * 64 + lane) * 8);
    float4 bo4 = *(const float4*)(BO4 + ct * 16 + 4 * g);
    const int qd = ct * 4 + g;
    const bool qv = qd < 5;
#pragma unroll
    for (int rtc = 0; rtc < 4; ++rtc) {
      f32x4 d = __builtin_amdgcn_mfma_f32_16x16x32_bf16(wof, mfB[rtc], zero4, 0, 0, 0);
      if (qv) {
        const int row = rtc * 16 + cl;
        unsigned u0 = cvt2(d[0] + bo4.x, d[1] + bo4.y);
        unsigned u1 = cvt2(d[2] + bo4.z, d[3] + bo4.w);
        *(uint2*)(slab + RB + row * 80 + qd * 8) = make_uint2(u0, u1);
      }
    }
  }
  FENCE();

  // ---------------- LN1 (x re-read from staged bf16 X rows) ------------------
  float y[20];
  if (active) {
    float ao[20], xr[20];
    unpack20_u2(slab + RB + lane * 80, ao);
    unpack20_u2(slab + RA + lane * 80, xr);
    float z[20];
#pragma unroll
    for (int d = 0; d < 20; ++d) z[d] = ao[d] + xr[d];
    float t0 = 0.f;
#pragma unroll
    for (int d = 0; d < 20; ++d) t0 += z[d];
    float mean = t0 * (1.0f / 20.0f);
    float var = 0.f;
#pragma unroll
    for (int d = 0; d < 20; ++d) { z[d] -= mean; var += z[d] * z[d]; }
    float rs = rsqrtf(var * (1.0f / 20.0f) + EPS);
#pragma unroll
    for (int d = 0; d < 20; ++d) y[d] = z[d] * rs * g1[d] + b1[d];
  } else {
#pragma unroll
    for (int d = 0; d < 20; ++d) y[d] = 0.f;
  }
  FENCE();  // X reads done before Y overlay of RA

  // ---------------- stage Y bf16 rows ----------------------------------------
  {
    unsigned u[10];
#pragma unroll
    for (int i = 0; i < 10; ++i) u[i] = cvt2(y[2 * i], y[2 * i + 1]);
    uint4* dst = (uint4*)(slab + RA + lane * 80);
    dst[0] = make_uint4(u[0], u[1], u[2], u[3]);
    dst[1] = make_uint4(u[4], u[5], u[6], u[7]);
    dst[2] = make_uint4(u[8], u[9], 0u, 0u);
    dst[3] = make_uint4(0u, 0u, 0u, 0u);
  }
  FENCE();

  // ---------------- FFN via MFMA (register-resident H, verified flow) --------
  bf16x8 ytf[4];
#pragma unroll
  for (int rt = 0; rt < 4; ++rt)
    ytf[rt] = *(const bf16x8*)(slab + RA + (rt * 16 + cl) * 80 + g * 16);

  f32x4 acc[4][2];
#pragma unroll
  for (int rt = 0; rt < 4; ++rt) { acc[rt][0] = zero4; acc[rt][1] = zero4; }

  for (int ch = 0; ch < 4; ++ch) {
#pragma unroll
    for (int q2 = 0; q2 < 4; ++q2) {
      const int fb = ch * 8 + q2 * 2;
      bf16x8 aw0 = *(const bf16x8*)(PA1 + (size_t)(fb * 64 + lane) * 8);
      bf16x8 aw1 = *(const bf16x8*)(PA1 + (size_t)((fb + 1) * 64 + lane) * 8);
      bf16x8 bw0 = *(const bf16x8*)(PB2 + (size_t)(fb * 64 + lane) * 8);
      bf16x8 bw1 = *(const bf16x8*)(PB2 + (size_t)((fb + 1) * 64 + lane) * 8);
#pragma unroll
      for (int rt = 0; rt < 4; ++rt) {
        f32x4 d0 = __builtin_amdgcn_mfma_f32_16x16x32_bf16(aw0, ytf[rt], zero4, 0, 0, 0);
        f32x4 d1 = __builtin_amdgcn_mfma_f32_16x16x32_bf16(aw1, ytf[rt], zero4, 0, 0, 0);
        union { bf16x8 v; unsigned uu[4]; } af;
        af.uu[0] = cvt2(fmaxf(d0[0], 0.f), fmaxf(d0[1], 0.f));
        af.uu[1] = cvt2(fmaxf(d0[2], 0.f), fmaxf(d0[3], 0.f));
        af.uu[2] = cvt2(fmaxf(d1[0], 0.f), fmaxf(d1[1], 0.f));
        af.uu[3] = cvt2(fmaxf(d1[2], 0.f), fmaxf(d1[3], 0.f));
        acc[rt][0] = __builtin_amdgcn_mfma_f32_16x16x32_bf16(af.v, bw0, acc[rt][0], 0, 0, 0);
        acc[rt][1] = __builtin_amdgcn_mfma_f32_16x16x32_bf16(af.v, bw1, acc[rt][1], 0, 0, 0);
      }
    }
  }

  // ---------------- LN2 in fragment space + store ----------------------------
  const float gg0 = g2[cl], bb0 = b2[cl];
  const float gg1 = (cl < 4) ? g2[16 + cl] : 0.f;
  const float bb1 = (cl < 4) ? b2[16 + cl] : 0.f;
  const long wrbase = wb * 63;
  const long total_rows = (long)B_TOT * S;

#pragma unroll
  for (int rt = 0; rt < 4; ++rt) {
#pragma unroll
    for (int r = 0; r < 4; ++r) {
      const int rrow = rt * 16 + 4 * g + r;
      float y0 = bf2f(*(const unsigned short*)(slab + RA + rrow * 80 + cl * 2));
      float y1 = (cl < 4) ? bf2f(*(const unsigned short*)(slab + RA + rrow * 80 + 32 + cl * 2)) : 0.f;
      float z0 = acc[rt][0][r] + y0;
      float z1 = acc[rt][1][r] + y1;
      float t = z0 + ((cl < 4) ? z1 : 0.f);
      t += __shfl_xor(t, 1, 16);
      t += __shfl_xor(t, 2, 16);
      t += __shfl_xor(t, 4, 16);
      t += __shfl_xor(t, 8, 16);
      float mean = t * (1.0f / 20.0f);
      float c0 = z0 - mean, c1 = z1 - mean;
      float vt = c0 * c0 + ((cl < 4) ? c1 * c1 : 0.f);
      vt += __shfl_xor(vt, 1, 16);
      vt += __shfl_xor(vt, 2, 16);
      vt += __shfl_xor(vt, 4, 16);
      vt += __shfl_xor(vt, 8, 16);
      float rs = rsqrtf(vt * (1.0f / 20.0f) + EPS);
      const long grow = wrbase + rrow;
      if (rrow < 63 && grow < total_rows) {
        Out[grow * 20 + cl] = c0 * rs * gg0 + bb0;
        if (cl < 4) Out[grow * 20 + 16 + cl] = c1 * rs * gg1 + bb1;
      }
    }
  }
}

extern "C" void kernel_launch(void* const* d_in, const int* in_sizes, int n_in,
                              void* d_out, int out_size, void* d_ws, size_t ws_size,
                              hipStream_t stream) {
  const float* X  = (const float*)d_in[0];
  const float* Wq = (const float*)d_in[1];
  const float* bq = (const float*)d_in[2];
  const float* Wk = (const float*)d_in[3];
  const float* bk = (const float*)d_in[4];
  const float* Wv = (const float*)d_in[5];
  const float* bv = (const float*)d_in[6];
  const float* Wo = (const float*)d_in[7];
  const float* bo = (const float*)d_in[8];
  const float* g1 = (const float*)d_in[9];
  const float* b1 = (const float*)d_in[10];
  const float* W1 = (const float*)d_in[11];
  const float* W2 = (const float*)d_in[12];
  const float* g2 = (const float*)d_in[13];
  const float* b2 = (const float*)d_in[14];
  float* Out = (float*)d_out;
  float* ws = (float*)d_ws;

  prep_kernel<<<144, 256, 0, stream>>>(Wq, Wk, Wv, Wo, W1, W2, bq, bk, bv, bo, ws);

  int nblocks = (B_TOT + 27) / 28;  // 4 waves/block * 7 batch elems/wave
  encoder_kernel<<<nblocks, 256, 0, stream>>>(X, ws, g1, b1, g2, b2, Out);
}